// Round 1
// baseline (703.641 us; speedup 1.0000x reference)
//
#include <hip/hip_runtime.h>
#include <hip/hip_bf16.h>

// EfficientAttention: B=4, N=8192, C=384, H=6, D=64
// Round 1: correctness-first fp32 implementation, 7 dispatches.

#define B 4
#define N 8192
#define C 384
#define H 6
#define D 64
#define BH (B * H)   // 24
#define BN (B * N)   // 32768

// ---------------------------------------------------------------------------
// Kernel 1: per-head QKV projection + q softmax (over D) + v scale.
// grid = BH * (N/64) blocks, 256 threads (4 waves; wave = 16 rows, lane = e).
// ---------------------------------------------------------------------------
__global__ __launch_bounds__(256) void proj_kernel(
    const float* __restrict__ x,
    const float* __restrict__ Wq, const float* __restrict__ bq,
    const float* __restrict__ Wk, const float* __restrict__ bk,
    const float* __restrict__ Wv, const float* __restrict__ bv,
    float* __restrict__ qout, float* __restrict__ kraw, float* __restrict__ vout)
{
    __shared__ float Wq_s[D * D];
    __shared__ float Wk_s[D * D];
    __shared__ float Wv_s[D * D];
    __shared__ float x_s[64 * D];

    const int blk = blockIdx.x;
    const int nb  = blk % (N / 64);
    const int bh  = blk / (N / 64);
    const int b   = bh / H;
    const int h   = bh % H;
    const int n0  = nb * 64;
    const int t   = threadIdx.x;

    // Stage W matrices for this head (16 KB each) via float4.
    const float4* Wq4 = (const float4*)(Wq + h * D * D);
    const float4* Wk4 = (const float4*)(Wk + h * D * D);
    const float4* Wv4 = (const float4*)(Wv + h * D * D);
    for (int i = t; i < D * D / 4; i += 256) {
        ((float4*)Wq_s)[i] = Wq4[i];
        ((float4*)Wk_s)[i] = Wk4[i];
        ((float4*)Wv_s)[i] = Wv4[i];
    }
    // Stage 64 rows of x for this head: row r -> x[(b*N + n0 + r)*C + h*D .. +63]
    for (int i = t; i < 64 * 16; i += 256) {
        int r = i >> 4, j = i & 15;
        const float4* src = (const float4*)(x + (size_t)(b * N + n0 + r) * C + h * D);
        ((float4*)(x_s + r * D))[j] = src[j];
    }
    __syncthreads();

    const int lane = t & 63;
    const int w    = t >> 6;
    const float bqv = bq[h * D + lane];
    const float bkv = bk[h * D + lane];
    const float bvv = bv[h * D + lane];

    for (int r = w * 16; r < w * 16 + 16; ++r) {
        float aq = bqv, ak = bkv, av = bvv;
        #pragma unroll 8
        for (int d = 0; d < D; ++d) {
            float xv = x_s[r * D + d];             // LDS broadcast
            aq += xv * Wq_s[d * D + lane];         // coalesced, 2-way (free)
            ak += xv * Wk_s[d * D + lane];
            av += xv * Wv_s[d * D + lane];
        }
        // q softmax over feature dim (full 64-lane wave)
        float m = aq;
        for (int o = 32; o; o >>= 1) m = fmaxf(m, __shfl_xor(m, o));
        float p = __expf(aq - m);
        float s = p;
        for (int o = 32; o; o >>= 1) s += __shfl_xor(s, o);
        float qv = p / s;

        size_t base = ((size_t)bh * N + n0 + r) * D + lane;
        qout[base] = qv;
        kraw[base] = ak;
        vout[base] = av * 0.125f;   // 1/sqrt(64)
    }
}

// ---------------------------------------------------------------------------
// Kernel 2: partial column stats for k softmax over N (online max/sum-exp).
// grid = BH * 16 (chunks of 512 rows), 256 threads.
// ---------------------------------------------------------------------------
__global__ __launch_bounds__(256) void kstat_partial(
    const float* __restrict__ kraw, float* __restrict__ pm, float* __restrict__ ps)
{
    const int bh = blockIdx.x >> 4;
    const int ch = blockIdx.x & 15;
    const int t = threadIdx.x, lane = t & 63, w = t >> 6;
    const float* base = kraw + ((size_t)bh * N + ch * 512) * D;

    float m = -1e30f, s = 0.f;
    for (int r = w; r < 512; r += 4) {
        float kval = base[r * D + lane];
        float mn = fmaxf(m, kval);
        s = s * __expf(m - mn) + __expf(kval - mn);
        m = mn;
    }
    __shared__ float sm[4][64];
    __shared__ float ss[4][64];
    sm[w][lane] = m; ss[w][lane] = s;
    __syncthreads();
    if (w == 0) {
        float M = sm[0][lane], S = ss[0][lane];
        #pragma unroll
        for (int i = 1; i < 4; ++i) {
            float mn = fmaxf(M, sm[i][lane]);
            S = S * __expf(M - mn) + ss[i][lane] * __expf(sm[i][lane] - mn);
            M = mn;
        }
        pm[(bh * 16 + ch) * 64 + lane] = M;
        ps[(bh * 16 + ch) * 64 + lane] = S;
    }
}

// grid = BH blocks, 64 threads: combine 16 partials per column.
__global__ void kstat_final(const float* __restrict__ pm, const float* __restrict__ ps,
                            float* __restrict__ mfin, float* __restrict__ zinv)
{
    const int bh = blockIdx.x;
    const int d = threadIdx.x;
    float M = -1e30f, S = 0.f;
    for (int c = 0; c < 16; ++c) {
        float m2 = pm[(bh * 16 + c) * 64 + d];
        float s2 = ps[(bh * 16 + c) * 64 + d];
        float mn = fmaxf(M, m2);
        S = S * __expf(M - mn) + s2 * __expf(m2 - mn);
        M = mn;
    }
    mfin[bh * 64 + d] = M;
    zinv[bh * 64 + d] = 1.f / S;
}

// ---------------------------------------------------------------------------
// Kernel 3: kv[bh][d][e] = sum_n softmax_n(k)[n,d] * v[n,e]  (atomic partials)
// grid = BH * 32 (chunks of 256 rows), 256 threads (16x16, 4x4 acc each).
// ---------------------------------------------------------------------------
__global__ __launch_bounds__(256) void kv_kernel(
    const float* __restrict__ kraw, const float* __restrict__ v,
    const float* __restrict__ mfin, const float* __restrict__ zinv,
    float* __restrict__ kv)
{
    const int bh = blockIdx.x >> 5;
    const int ch = blockIdx.x & 31;
    const int t = threadIdx.x;
    const int lane = t & 63;
    const int eg = t & 15;        // e tile (4 cols)
    const int dg = t >> 4;        // d tile (4 rows)

    __shared__ float k_s[64 * 64];
    __shared__ float v_s[64 * 64];

    // Each staging thread always loads column (t & 63) since stride 256 % 64 == 0.
    const float mcol = mfin[bh * 64 + lane];
    const float zcol = zinv[bh * 64 + lane];

    const float* kb = kraw + ((size_t)bh * N + ch * 256) * D;
    const float* vb = v    + ((size_t)bh * N + ch * 256) * D;

    float acc[4][4] = {};

    for (int sub = 0; sub < 4; ++sub) {
        __syncthreads();
        for (int i = t; i < 64 * 64; i += 256) {
            k_s[i] = __expf(kb[sub * 64 * 64 + i] - mcol) * zcol;
            v_s[i] = vb[sub * 64 * 64 + i];
        }
        __syncthreads();
        for (int r = 0; r < 64; ++r) {
            float kvals[4], vvals[4];
            #pragma unroll
            for (int i = 0; i < 4; ++i) kvals[i] = k_s[r * 64 + dg * 4 + i];
            #pragma unroll
            for (int j = 0; j < 4; ++j) vvals[j] = v_s[r * 64 + eg * 4 + j];
            #pragma unroll
            for (int i = 0; i < 4; ++i)
                #pragma unroll
                for (int j = 0; j < 4; ++j) acc[i][j] += kvals[i] * vvals[j];
        }
    }

    float* kvb = kv + bh * (D * D);
    #pragma unroll
    for (int i = 0; i < 4; ++i)
        #pragma unroll
        for (int j = 0; j < 4; ++j)
            atomicAdd(&kvb[(dg * 4 + i) * 64 + eg * 4 + j], acc[i][j]);
}

// ---------------------------------------------------------------------------
// Kernel 4: att[b,n,h*64+e] = sum_d q[bh,n,d] * kv[bh,d,e]
// grid = BH * 32 (chunks of 256 rows), 256 threads (4 waves, lane = e).
// ---------------------------------------------------------------------------
__global__ __launch_bounds__(256) void attq_kernel(
    const float* __restrict__ q, const float* __restrict__ kv, float* __restrict__ att)
{
    const int bh = blockIdx.x >> 5;
    const int ch = blockIdx.x & 31;
    const int b = bh / H, h = bh % H;
    const int t = threadIdx.x, lane = t & 63, w = t >> 6;

    __shared__ float kv_s[64 * 64];
    __shared__ float q_s[64 * 64];

    for (int i = t; i < D * D; i += 256) kv_s[i] = kv[bh * (D * D) + i];

    const float* qb = q + ((size_t)bh * N + ch * 256) * D;

    for (int sub = 0; sub < 4; ++sub) {
        __syncthreads();                       // kv_s ready (sub=0) / q_s reuse safe
        for (int i = t; i < 64 * 64; i += 256) q_s[i] = qb[sub * 64 * 64 + i];
        __syncthreads();
        for (int r = w * 16; r < w * 16 + 16; ++r) {
            float acc = 0.f;
            #pragma unroll 8
            for (int d = 0; d < 64; ++d) acc += q_s[r * 64 + d] * kv_s[d * 64 + lane];
            int n = ch * 256 + sub * 64 + r;
            att[(size_t)(b * N + n) * C + h * D + lane] = acc;
        }
    }
}

// ---------------------------------------------------------------------------
// Kernel 5: out[m][c] = sum_k att[m][k] * Wp[c][k] + bp[c]
// grid = (BN/64) * (C/64) = 3072 blocks, 256 threads, 64x64 tile, 4x4 acc.
// ---------------------------------------------------------------------------
__global__ __launch_bounds__(256) void final_gemm(
    const float* __restrict__ att, const float* __restrict__ Wp,
    const float* __restrict__ bp, float* __restrict__ out)
{
    __shared__ float A_s[64 * 65];   // +1 pad: kills same-bank stride-64 conflicts
    __shared__ float W_s[64 * 65];

    const int mt = blockIdx.x / (C / 64);
    const int ct = blockIdx.x % (C / 64);
    const int m0 = mt * 64, c0 = ct * 64;
    const int t = threadIdx.x;
    const int cg = t & 15;    // 4 cols each
    const int mg = t >> 4;    // 4 rows each

    float acc[4][4] = {};

    for (int ks = 0; ks < C / 64; ++ks) {
        __syncthreads();
        for (int i = t; i < 4096; i += 256) {
            int r = i >> 6, kk = i & 63;
            A_s[r * 65 + kk] = att[(size_t)(m0 + r) * C + ks * 64 + kk];
            W_s[r * 65 + kk] = Wp[(size_t)(c0 + r) * C + ks * 64 + kk];
        }
        __syncthreads();
        for (int kk = 0; kk < 64; ++kk) {
            float a[4], w[4];
            #pragma unroll
            for (int i = 0; i < 4; ++i) a[i] = A_s[(mg * 4 + i) * 65 + kk];
            #pragma unroll
            for (int j = 0; j < 4; ++j) w[j] = W_s[(cg * 4 + j) * 65 + kk];
            #pragma unroll
            for (int i = 0; i < 4; ++i)
                #pragma unroll
                for (int j = 0; j < 4; ++j) acc[i][j] += a[i] * w[j];
        }
    }

    #pragma unroll
    for (int i = 0; i < 4; ++i) {
        int m = m0 + mg * 4 + i;
        #pragma unroll
        for (int j = 0; j < 4; ++j) {
            int c = c0 + cg * 4 + j;
            out[(size_t)m * C + c] = acc[i][j] + bp[c];
        }
    }
}

// ---------------------------------------------------------------------------
extern "C" void kernel_launch(void* const* d_in, const int* in_sizes, int n_in,
                              void* d_out, int out_size, void* d_ws, size_t ws_size,
                              hipStream_t stream)
{
    const float* x  = (const float*)d_in[0];
    const float* Wq = (const float*)d_in[1];
    const float* bq = (const float*)d_in[2];
    const float* Wk = (const float*)d_in[3];
    const float* bk = (const float*)d_in[4];
    const float* Wv = (const float*)d_in[5];
    const float* bv = (const float*)d_in[6];
    const float* Wp = (const float*)d_in[7];
    const float* bp = (const float*)d_in[8];
    float* out = (float*)d_out;

    const size_t SZ = (size_t)B * H * N * D;   // 12,582,912 floats
    float* ws   = (float*)d_ws;
    float* q    = ws;                           // [BH, N, D]
    float* kraw = ws + SZ;                      // [BH, N, D]  (reused as att)
    float* vs   = ws + 2 * SZ;                  // [BH, N, D]
    float* kv   = ws + 3 * SZ;                  // [BH, D, D]
    float* pm   = kv + BH * D * D;              // [BH*16, 64]
    float* ps   = pm + BH * 16 * 64;
    float* mfin = ps + BH * 16 * 64;            // [BH, 64]
    float* zinv = mfin + BH * 64;
    float* att  = kraw;                         // reuse after kv_kernel

    proj_kernel<<<BH * (N / 64), 256, 0, stream>>>(x, Wq, bq, Wk, bk, Wv, bv,
                                                   q, kraw, vs);
    kstat_partial<<<BH * 16, 256, 0, stream>>>(kraw, pm, ps);
    kstat_final<<<BH, 64, 0, stream>>>(pm, ps, mfin, zinv);
    hipMemsetAsync(kv, 0, (size_t)BH * D * D * sizeof(float), stream);
    kv_kernel<<<BH * 32, 256, 0, stream>>>(kraw, vs, mfin, zinv, kv);
    attq_kernel<<<BH * 32, 256, 0, stream>>>(q, kv, att);
    final_gemm<<<(BN / 64) * (C / 64), 256, 0, stream>>>(att, Wp, bp, out);
}

// Round 2
// 429.563 us; speedup vs baseline: 1.6380x; 1.6380x over previous
//
#include <hip/hip_runtime.h>
#include <hip/hip_bf16.h>

// EfficientAttention: B=4, N=8192, C=384, H=6, D=64
// Round 2: fp32, proj 4x4-tile fused-3-matrix rewrite; attq+final fused via
// KW = kv @ Wp^T precompute. 6 compute dispatches + 1 memset.

#define B 4
#define N 8192
#define C 384
#define H 6
#define D 64
#define BH (B * H)   // 24
#define BN (B * N)   // 32768

// ---------------------------------------------------------------------------
// Kernel 1: per-head QKV projection + q softmax (over D) + v scale.
// grid = BH * (N/64), 256 threads. Thread tile 4 rows x 4 cols.
// x staged transposed [k][m] so A-operand is one ds_read_b128; the single
// x read feeds all three weight matrices (48 FMA per 4 b128 reads).
// ---------------------------------------------------------------------------
__global__ __launch_bounds__(256) void proj_kernel(
    const float* __restrict__ x,
    const float* __restrict__ Wq, const float* __restrict__ bq,
    const float* __restrict__ Wk, const float* __restrict__ bk,
    const float* __restrict__ Wv, const float* __restrict__ bv,
    float* __restrict__ qout, float* __restrict__ kraw, float* __restrict__ vout)
{
    __shared__ float x_s[64 * 68];    // [d][r], pad->68 keeps b128 16B-aligned
    __shared__ float Wq_s[64 * 64];   // [d][c]
    __shared__ float Wk_s[64 * 64];
    __shared__ float Wv_s[64 * 64];

    const int blk = blockIdx.x;
    const int nb  = blk % (N / 64);
    const int bh  = blk / (N / 64);
    const int b   = bh / H;
    const int h   = bh % H;
    const int n0  = nb * 64;
    const int t   = threadIdx.x;
    const int mg  = t >> 4;   // row group: rows mg*4..mg*4+3
    const int cg  = t & 15;   // col group: cols cg*4..cg*4+3

    const float4* Wq4 = (const float4*)(Wq + h * D * D);
    const float4* Wk4 = (const float4*)(Wk + h * D * D);
    const float4* Wv4 = (const float4*)(Wv + h * D * D);
    for (int i = t; i < 1024; i += 256) {
        ((float4*)Wq_s)[i] = Wq4[i];
        ((float4*)Wk_s)[i] = Wk4[i];
        ((float4*)Wv_s)[i] = Wv4[i];
    }
    for (int i = t; i < 1024; i += 256) {
        int r = i >> 4, j = i & 15;
        float4 xv = *(const float4*)(x + (size_t)(b * N + n0 + r) * C + h * D + 4 * j);
        x_s[(4 * j + 0) * 68 + r] = xv.x;
        x_s[(4 * j + 1) * 68 + r] = xv.y;
        x_s[(4 * j + 2) * 68 + r] = xv.z;
        x_s[(4 * j + 3) * 68 + r] = xv.w;
    }
    __syncthreads();

    float aq[4][4] = {}, ak[4][4] = {}, av[4][4] = {};
    #pragma unroll 4
    for (int d = 0; d < 64; ++d) {
        float4 a  = *(float4*)&x_s[d * 68 + mg * 4];
        float4 wq = *(float4*)&Wq_s[d * 64 + cg * 4];
        float4 wk = *(float4*)&Wk_s[d * 64 + cg * 4];
        float4 wv = *(float4*)&Wv_s[d * 64 + cg * 4];
        const float av4[4] = {a.x, a.y, a.z, a.w};
        const float q4[4] = {wq.x, wq.y, wq.z, wq.w};
        const float k4[4] = {wk.x, wk.y, wk.z, wk.w};
        const float v4[4] = {wv.x, wv.y, wv.z, wv.w};
        #pragma unroll
        for (int i = 0; i < 4; ++i)
            #pragma unroll
            for (int j = 0; j < 4; ++j) {
                aq[i][j] += av4[i] * q4[j];
                ak[i][j] += av4[i] * k4[j];
                av[i][j] += av4[i] * v4[j];
            }
    }

    const float4 bq4 = *(const float4*)(bq + h * D + cg * 4);
    const float4 bk4 = *(const float4*)(bk + h * D + cg * 4);
    const float4 bv4 = *(const float4*)(bv + h * D + cg * 4);

    #pragma unroll
    for (int i = 0; i < 4; ++i) {
        const size_t rowbase = ((size_t)bh * N + n0 + mg * 4 + i) * D + cg * 4;
        // q: bias + softmax over the row (16 cg lanes x 4 cols, same wave)
        float v0 = aq[i][0] + bq4.x, v1 = aq[i][1] + bq4.y;
        float v2 = aq[i][2] + bq4.z, v3 = aq[i][3] + bq4.w;
        float m = fmaxf(fmaxf(v0, v1), fmaxf(v2, v3));
        #pragma unroll
        for (int msk = 1; msk < 16; msk <<= 1) m = fmaxf(m, __shfl_xor(m, msk));
        float e0 = __expf(v0 - m), e1 = __expf(v1 - m);
        float e2 = __expf(v2 - m), e3 = __expf(v3 - m);
        float s = e0 + e1 + e2 + e3;
        #pragma unroll
        for (int msk = 1; msk < 16; msk <<= 1) s += __shfl_xor(s, msk);
        float inv = 1.f / s;
        float4 qo = {e0 * inv, e1 * inv, e2 * inv, e3 * inv};
        *(float4*)&qout[rowbase] = qo;
        // k: bias only
        float4 ko = {ak[i][0] + bk4.x, ak[i][1] + bk4.y,
                     ak[i][2] + bk4.z, ak[i][3] + bk4.w};
        *(float4*)&kraw[rowbase] = ko;
        // v: bias + 1/sqrt(D)
        float4 vo = {(av[i][0] + bv4.x) * 0.125f, (av[i][1] + bv4.y) * 0.125f,
                     (av[i][2] + bv4.z) * 0.125f, (av[i][3] + bv4.w) * 0.125f};
        *(float4*)&vout[rowbase] = vo;
    }
}

// ---------------------------------------------------------------------------
// Kernel 2: partial column stats for k softmax over N (online max/sum-exp).
// ---------------------------------------------------------------------------
__global__ __launch_bounds__(256) void kstat_partial(
    const float* __restrict__ kraw, float* __restrict__ pm, float* __restrict__ ps)
{
    const int bh = blockIdx.x >> 4;
    const int ch = blockIdx.x & 15;
    const int t = threadIdx.x, lane = t & 63, w = t >> 6;
    const float* base = kraw + ((size_t)bh * N + ch * 512) * D;

    float m = -1e30f, s = 0.f;
    for (int r = w; r < 512; r += 4) {
        float kval = base[r * D + lane];
        float mn = fmaxf(m, kval);
        s = s * __expf(m - mn) + __expf(kval - mn);
        m = mn;
    }
    __shared__ float sm[4][64];
    __shared__ float ss[4][64];
    sm[w][lane] = m; ss[w][lane] = s;
    __syncthreads();
    if (w == 0) {
        float M = sm[0][lane], S = ss[0][lane];
        #pragma unroll
        for (int i = 1; i < 4; ++i) {
            float mn = fmaxf(M, sm[i][lane]);
            S = S * __expf(M - mn) + ss[i][lane] * __expf(sm[i][lane] - mn);
            M = mn;
        }
        pm[(bh * 16 + ch) * 64 + lane] = M;
        ps[(bh * 16 + ch) * 64 + lane] = S;
    }
}

__global__ void kstat_final(const float* __restrict__ pm, const float* __restrict__ ps,
                            float* __restrict__ mfin, float* __restrict__ zinv)
{
    const int bh = blockIdx.x;
    const int d = threadIdx.x;
    float M = -1e30f, S = 0.f;
    for (int c = 0; c < 16; ++c) {
        float m2 = pm[(bh * 16 + c) * 64 + d];
        float s2 = ps[(bh * 16 + c) * 64 + d];
        float mn = fmaxf(M, m2);
        S = S * __expf(M - mn) + s2 * __expf(m2 - mn);
        M = mn;
    }
    mfin[bh * 64 + d] = M;
    zinv[bh * 64 + d] = 1.f / S;
}

// ---------------------------------------------------------------------------
// Kernel 3: kv[bh][d][e] = sum_n softmax_n(k)[n,d] * v[n,e]  (atomic partials)
// ---------------------------------------------------------------------------
__global__ __launch_bounds__(256) void kv_kernel(
    const float* __restrict__ kraw, const float* __restrict__ v,
    const float* __restrict__ mfin, const float* __restrict__ zinv,
    float* __restrict__ kv)
{
    const int bh = blockIdx.x >> 5;
    const int ch = blockIdx.x & 31;
    const int t = threadIdx.x;
    const int lane = t & 63;
    const int eg = t & 15;
    const int dg = t >> 4;

    __shared__ float k_s[64 * 64];
    __shared__ float v_s[64 * 64];

    const float mcol = mfin[bh * 64 + lane];
    const float zcol = zinv[bh * 64 + lane];

    const float* kb = kraw + ((size_t)bh * N + ch * 256) * D;
    const float* vb = v    + ((size_t)bh * N + ch * 256) * D;

    float acc[4][4] = {};

    for (int sub = 0; sub < 4; ++sub) {
        __syncthreads();
        for (int i = t; i < 64 * 64; i += 256) {
            k_s[i] = __expf(kb[sub * 64 * 64 + i] - mcol) * zcol;
            v_s[i] = vb[sub * 64 * 64 + i];
        }
        __syncthreads();
        for (int r = 0; r < 64; ++r) {
            float4 kf = *(float4*)&k_s[r * 64 + dg * 4];
            float4 vf = *(float4*)&v_s[r * 64 + eg * 4];
            const float kk[4] = {kf.x, kf.y, kf.z, kf.w};
            const float vv[4] = {vf.x, vf.y, vf.z, vf.w};
            #pragma unroll
            for (int i = 0; i < 4; ++i)
                #pragma unroll
                for (int j = 0; j < 4; ++j) acc[i][j] += kk[i] * vv[j];
        }
    }

    float* kvb = kv + bh * (D * D);
    #pragma unroll
    for (int i = 0; i < 4; ++i)
        #pragma unroll
        for (int j = 0; j < 4; ++j)
            atomicAdd(&kvb[(dg * 4 + i) * 64 + eg * 4 + j], acc[i][j]);
}

// ---------------------------------------------------------------------------
// Kernel 4: KW[bh][d][c] = sum_e kv[bh][d][e] * Wp[c][h*64+e]
// grid = BH * (C/64) = 144 blocks, 256 threads, 4x4 tiles. Tiny (75 MFLOP).
// ---------------------------------------------------------------------------
__global__ __launch_bounds__(256) void kw_kernel(
    const float* __restrict__ kv, const float* __restrict__ Wp, float* __restrict__ KW)
{
    __shared__ float kv_s[64 * 68];   // [e][d]
    __shared__ float w_s[64 * 68];    // [e][c]
    const int bh = blockIdx.x / (C / 64);
    const int ct = blockIdx.x % (C / 64);
    const int h = bh % H;
    const int c0 = ct * 64;
    const int t = threadIdx.x, dg = t >> 4, cg = t & 15;

    for (int i = t; i < 4096; i += 256) {
        int row = i >> 6, e = i & 63;
        kv_s[e * 68 + row] = kv[bh * (D * D) + row * 64 + e];            // [d][e]->[e][d]
        w_s[e * 68 + row]  = Wp[(size_t)(c0 + row) * C + h * 64 + e];    // [c][e]->[e][c]
    }
    __syncthreads();

    float acc[4][4] = {};
    for (int e = 0; e < 64; ++e) {
        float4 a = *(float4*)&kv_s[e * 68 + dg * 4];
        float4 w = *(float4*)&w_s[e * 68 + cg * 4];
        const float a4[4] = {a.x, a.y, a.z, a.w};
        const float w4[4] = {w.x, w.y, w.z, w.w};
        #pragma unroll
        for (int i = 0; i < 4; ++i)
            #pragma unroll
            for (int j = 0; j < 4; ++j) acc[i][j] += a4[i] * w4[j];
    }
    #pragma unroll
    for (int i = 0; i < 4; ++i) {
        float4 o = {acc[i][0], acc[i][1], acc[i][2], acc[i][3]};
        *(float4*)&KW[((size_t)bh * 64 + dg * 4 + i) * C + c0 + cg * 4] = o;
    }
}

// ---------------------------------------------------------------------------
// Kernel 5: out[b*N+n][c] = sum_{h,d} q[bh][n][d] * KW[bh][d][c] + bp[c]
// grid = (BN/128) * (C/128) = 768 blocks, 256 threads, 8x8 thread tile, BK=32.
// k-chunk kc -> head kc>>1, offset (kc&1)*32; q k-slices are contiguous.
// ---------------------------------------------------------------------------
__global__ __launch_bounds__(256) void out_gemm(
    const float* __restrict__ q, const float* __restrict__ KW,
    const float* __restrict__ bp, float* __restrict__ out)
{
    __shared__ float q_s[32 * 132];    // [kk][m] transposed, pad 132 (16B-aligned)
    __shared__ float kw_s[32 * 128];   // [kk][c]

    const int mt = blockIdx.x / (C / 128);
    const int ct = blockIdx.x % (C / 128);
    const int m0 = mt * 128, c0 = ct * 128;
    const int b  = m0 >> 13;          // N = 8192
    const int n0 = m0 & (N - 1);
    const int t  = threadIdx.x;
    const int mg = t >> 4;            // 16 groups x 8 rows
    const int cg = t & 15;            // 16 groups x 8 cols

    float acc[8][8] = {};

    for (int kc = 0; kc < C / 32; ++kc) {
        const int h  = kc >> 1;
        const int ko = (kc & 1) * 32;
        __syncthreads();
        for (int i = t; i < 1024; i += 256) {
            int r = i >> 3, j = i & 7;
            float4 v = *(const float4*)(q + ((size_t)(b * H + h) * N + n0 + r) * D + ko + 4 * j);
            q_s[(4 * j + 0) * 132 + r] = v.x;
            q_s[(4 * j + 1) * 132 + r] = v.y;
            q_s[(4 * j + 2) * 132 + r] = v.z;
            q_s[(4 * j + 3) * 132 + r] = v.w;
        }
        for (int i = t; i < 1024; i += 256) {
            int kk = i >> 5, j = i & 31;
            *(float4*)&kw_s[kk * 128 + 4 * j] =
                *(const float4*)(KW + ((size_t)(b * H + h) * 64 + ko + kk) * C + c0 + 4 * j);
        }
        __syncthreads();
        #pragma unroll 4
        for (int kk = 0; kk < 32; ++kk) {
            float a[8], w[8];
            *(float4*)&a[0] = *(float4*)&q_s[kk * 132 + mg * 8];
            *(float4*)&a[4] = *(float4*)&q_s[kk * 132 + mg * 8 + 4];
            *(float4*)&w[0] = *(float4*)&kw_s[kk * 128 + cg * 8];
            *(float4*)&w[4] = *(float4*)&kw_s[kk * 128 + cg * 8 + 4];
            #pragma unroll
            for (int i = 0; i < 8; ++i)
                #pragma unroll
                for (int j = 0; j < 8; ++j) acc[i][j] += a[i] * w[j];
        }
    }

    float bpv[8];
    *(float4*)&bpv[0] = *(const float4*)(bp + c0 + cg * 8);
    *(float4*)&bpv[4] = *(const float4*)(bp + c0 + cg * 8 + 4);
    #pragma unroll
    for (int i = 0; i < 8; ++i) {
        size_t row = (size_t)m0 + mg * 8 + i;
        float4 o0 = {acc[i][0] + bpv[0], acc[i][1] + bpv[1],
                     acc[i][2] + bpv[2], acc[i][3] + bpv[3]};
        float4 o1 = {acc[i][4] + bpv[4], acc[i][5] + bpv[5],
                     acc[i][6] + bpv[6], acc[i][7] + bpv[7]};
        *(float4*)&out[row * C + c0 + cg * 8]     = o0;
        *(float4*)&out[row * C + c0 + cg * 8 + 4] = o1;
    }
}

// ---------------------------------------------------------------------------
extern "C" void kernel_launch(void* const* d_in, const int* in_sizes, int n_in,
                              void* d_out, int out_size, void* d_ws, size_t ws_size,
                              hipStream_t stream)
{
    const float* x  = (const float*)d_in[0];
    const float* Wq = (const float*)d_in[1];
    const float* bq = (const float*)d_in[2];
    const float* Wk = (const float*)d_in[3];
    const float* bk = (const float*)d_in[4];
    const float* Wv = (const float*)d_in[5];
    const float* bv = (const float*)d_in[6];
    const float* Wp = (const float*)d_in[7];
    const float* bp = (const float*)d_in[8];
    float* out = (float*)d_out;

    const size_t SZ = (size_t)B * H * N * D;
    float* ws   = (float*)d_ws;
    float* q    = ws;                           // [BH, N, D]
    float* kraw = ws + SZ;                      // [BH, N, D]
    float* vs   = ws + 2 * SZ;                  // [BH, N, D]
    float* kv   = ws + 3 * SZ;                  // [BH, D, D]
    float* pm   = kv + BH * D * D;              // [BH*16, 64]
    float* ps   = pm + BH * 16 * 64;
    float* mfin = ps + BH * 16 * 64;            // [BH, 64]
    float* zinv = mfin + BH * 64;
    float* KW   = zinv + BH * 64;               // [BH, D, C]

    proj_kernel<<<BH * (N / 64), 256, 0, stream>>>(x, Wq, bq, Wk, bk, Wv, bv,
                                                   q, kraw, vs);
    kstat_partial<<<BH * 16, 256, 0, stream>>>(kraw, pm, ps);
    kstat_final<<<BH, 64, 0, stream>>>(pm, ps, mfin, zinv);
    hipMemsetAsync(kv, 0, (size_t)BH * D * D * sizeof(float), stream);
    kv_kernel<<<BH * 32, 256, 0, stream>>>(kraw, vs, mfin, zinv, kv);
    kw_kernel<<<BH * (C / 64), 256, 0, stream>>>(kv, Wp, KW);
    out_gemm<<<(BN / 128) * (C / 128), 256, 0, stream>>>(q, KW, bp, out);
}

// Round 3
// 317.362 us; speedup vs baseline: 2.2172x; 1.3535x over previous
//
#include <hip/hip_runtime.h>
#include <hip/hip_bf16.h>

// EfficientAttention: B=4, N=8192, C=384, H=6, D=64
// Round 3: out_gemm -> bf16 MFMA (16x16x32), q + KW stored bf16.
// KW precomputed transposed [b][c][k] so the B-fragment is one 16B LDS read.

#define B 4
#define N 8192
#define C 384
#define H 6
#define D 64
#define BH (B * H)   // 24
#define BN (B * N)   // 32768

typedef __attribute__((ext_vector_type(8))) short short8;
typedef __attribute__((ext_vector_type(4))) float f32x4;

__device__ inline unsigned short f2bf(float f) {
    unsigned int u = __float_as_uint(f);
    unsigned int r = (u + 0x7fff + ((u >> 16) & 1)) >> 16;   // RNE
    return (unsigned short)r;
}

// ---------------------------------------------------------------------------
// Kernel 1: per-head QKV projection + q softmax (over D, -> bf16) + v scale.
// grid = BH * (N/64), 256 threads, 4x4 thread tiles, fused 3-matrix inner loop.
// ---------------------------------------------------------------------------
__global__ __launch_bounds__(256) void proj_kernel(
    const float* __restrict__ x,
    const float* __restrict__ Wq, const float* __restrict__ bq,
    const float* __restrict__ Wk, const float* __restrict__ bk,
    const float* __restrict__ Wv, const float* __restrict__ bv,
    unsigned short* __restrict__ qout, float* __restrict__ kraw,
    float* __restrict__ vout)
{
    __shared__ float x_s[64 * 68];    // [d][r] transposed, pad 68
    __shared__ float Wq_s[64 * 64];   // [d][c]
    __shared__ float Wk_s[64 * 64];
    __shared__ float Wv_s[64 * 64];

    const int blk = blockIdx.x;
    const int nb  = blk % (N / 64);
    const int bh  = blk / (N / 64);
    const int b   = bh / H;
    const int h   = bh % H;
    const int n0  = nb * 64;
    const int t   = threadIdx.x;
    const int mg  = t >> 4;
    const int cg  = t & 15;

    const float4* Wq4 = (const float4*)(Wq + h * D * D);
    const float4* Wk4 = (const float4*)(Wk + h * D * D);
    const float4* Wv4 = (const float4*)(Wv + h * D * D);
    for (int i = t; i < 1024; i += 256) {
        ((float4*)Wq_s)[i] = Wq4[i];
        ((float4*)Wk_s)[i] = Wk4[i];
        ((float4*)Wv_s)[i] = Wv4[i];
    }
    for (int i = t; i < 1024; i += 256) {
        int r = i >> 4, j = i & 15;
        float4 xv = *(const float4*)(x + (size_t)(b * N + n0 + r) * C + h * D + 4 * j);
        x_s[(4 * j + 0) * 68 + r] = xv.x;
        x_s[(4 * j + 1) * 68 + r] = xv.y;
        x_s[(4 * j + 2) * 68 + r] = xv.z;
        x_s[(4 * j + 3) * 68 + r] = xv.w;
    }
    __syncthreads();

    float aq[4][4] = {}, ak[4][4] = {}, av[4][4] = {};
    #pragma unroll 4
    for (int d = 0; d < 64; ++d) {
        float4 a  = *(float4*)&x_s[d * 68 + mg * 4];
        float4 wq = *(float4*)&Wq_s[d * 64 + cg * 4];
        float4 wk = *(float4*)&Wk_s[d * 64 + cg * 4];
        float4 wv = *(float4*)&Wv_s[d * 64 + cg * 4];
        const float av4[4] = {a.x, a.y, a.z, a.w};
        const float q4[4] = {wq.x, wq.y, wq.z, wq.w};
        const float k4[4] = {wk.x, wk.y, wk.z, wk.w};
        const float v4[4] = {wv.x, wv.y, wv.z, wv.w};
        #pragma unroll
        for (int i = 0; i < 4; ++i)
            #pragma unroll
            for (int j = 0; j < 4; ++j) {
                aq[i][j] += av4[i] * q4[j];
                ak[i][j] += av4[i] * k4[j];
                av[i][j] += av4[i] * v4[j];
            }
    }

    const float4 bq4 = *(const float4*)(bq + h * D + cg * 4);
    const float4 bk4 = *(const float4*)(bk + h * D + cg * 4);
    const float4 bv4 = *(const float4*)(bv + h * D + cg * 4);

    #pragma unroll
    for (int i = 0; i < 4; ++i) {
        const size_t rowbase = ((size_t)bh * N + n0 + mg * 4 + i) * D + cg * 4;
        float v0 = aq[i][0] + bq4.x, v1 = aq[i][1] + bq4.y;
        float v2 = aq[i][2] + bq4.z, v3 = aq[i][3] + bq4.w;
        float m = fmaxf(fmaxf(v0, v1), fmaxf(v2, v3));
        #pragma unroll
        for (int msk = 1; msk < 16; msk <<= 1) m = fmaxf(m, __shfl_xor(m, msk));
        float e0 = __expf(v0 - m), e1 = __expf(v1 - m);
        float e2 = __expf(v2 - m), e3 = __expf(v3 - m);
        float s = e0 + e1 + e2 + e3;
        #pragma unroll
        for (int msk = 1; msk < 16; msk <<= 1) s += __shfl_xor(s, msk);
        float inv = 1.f / s;
        ushort4 qo = {f2bf(e0 * inv), f2bf(e1 * inv), f2bf(e2 * inv), f2bf(e3 * inv)};
        *(ushort4*)&qout[rowbase] = qo;
        float4 ko = {ak[i][0] + bk4.x, ak[i][1] + bk4.y,
                     ak[i][2] + bk4.z, ak[i][3] + bk4.w};
        *(float4*)&kraw[rowbase] = ko;
        float4 vo = {(av[i][0] + bv4.x) * 0.125f, (av[i][1] + bv4.y) * 0.125f,
                     (av[i][2] + bv4.z) * 0.125f, (av[i][3] + bv4.w) * 0.125f};
        *(float4*)&vout[rowbase] = vo;
    }
}

// ---------------------------------------------------------------------------
// Kernel 2: partial column stats for k softmax over N (online max/sum-exp).
// ---------------------------------------------------------------------------
__global__ __launch_bounds__(256) void kstat_partial(
    const float* __restrict__ kraw, float* __restrict__ pm, float* __restrict__ ps)
{
    const int bh = blockIdx.x >> 4;
    const int ch = blockIdx.x & 15;
    const int t = threadIdx.x, lane = t & 63, w = t >> 6;
    const float* base = kraw + ((size_t)bh * N + ch * 512) * D;

    float m = -1e30f, s = 0.f;
    for (int r = w; r < 512; r += 4) {
        float kval = base[r * D + lane];
        float mn = fmaxf(m, kval);
        s = s * __expf(m - mn) + __expf(kval - mn);
        m = mn;
    }
    __shared__ float sm[4][64];
    __shared__ float ss[4][64];
    sm[w][lane] = m; ss[w][lane] = s;
    __syncthreads();
    if (w == 0) {
        float M = sm[0][lane], S = ss[0][lane];
        #pragma unroll
        for (int i = 1; i < 4; ++i) {
            float mn = fmaxf(M, sm[i][lane]);
            S = S * __expf(M - mn) + ss[i][lane] * __expf(sm[i][lane] - mn);
            M = mn;
        }
        pm[(bh * 16 + ch) * 64 + lane] = M;
        ps[(bh * 16 + ch) * 64 + lane] = S;
    }
}

__global__ void kstat_final(const float* __restrict__ pm, const float* __restrict__ ps,
                            float* __restrict__ mfin, float* __restrict__ zinv)
{
    const int bh = blockIdx.x;
    const int d = threadIdx.x;
    float M = -1e30f, S = 0.f;
    for (int c = 0; c < 16; ++c) {
        float m2 = pm[(bh * 16 + c) * 64 + d];
        float s2 = ps[(bh * 16 + c) * 64 + d];
        float mn = fmaxf(M, m2);
        S = S * __expf(M - mn) + s2 * __expf(m2 - mn);
        M = mn;
    }
    mfin[bh * 64 + d] = M;
    zinv[bh * 64 + d] = 1.f / S;
}

// ---------------------------------------------------------------------------
// Kernel 3: kv[bh][d][e] = sum_n softmax_n(k)[n,d] * v[n,e]  (atomic partials)
// ---------------------------------------------------------------------------
__global__ __launch_bounds__(256) void kv_kernel(
    const float* __restrict__ kraw, const float* __restrict__ v,
    const float* __restrict__ mfin, const float* __restrict__ zinv,
    float* __restrict__ kv)
{
    const int bh = blockIdx.x >> 5;
    const int ch = blockIdx.x & 31;
    const int t = threadIdx.x;
    const int lane = t & 63;
    const int eg = t & 15;
    const int dg = t >> 4;

    __shared__ float k_s[64 * 64];
    __shared__ float v_s[64 * 64];

    const float mcol = mfin[bh * 64 + lane];
    const float zcol = zinv[bh * 64 + lane];

    const float* kb = kraw + ((size_t)bh * N + ch * 256) * D;
    const float* vb = v    + ((size_t)bh * N + ch * 256) * D;

    float acc[4][4] = {};

    for (int sub = 0; sub < 4; ++sub) {
        __syncthreads();
        for (int i = t; i < 64 * 64; i += 256) {
            k_s[i] = __expf(kb[sub * 64 * 64 + i] - mcol) * zcol;
            v_s[i] = vb[sub * 64 * 64 + i];
        }
        __syncthreads();
        for (int r = 0; r < 64; ++r) {
            float4 kf = *(float4*)&k_s[r * 64 + dg * 4];
            float4 vf = *(float4*)&v_s[r * 64 + eg * 4];
            const float kk[4] = {kf.x, kf.y, kf.z, kf.w};
            const float vv[4] = {vf.x, vf.y, vf.z, vf.w};
            #pragma unroll
            for (int i = 0; i < 4; ++i)
                #pragma unroll
                for (int j = 0; j < 4; ++j) acc[i][j] += kk[i] * vv[j];
        }
    }

    float* kvb = kv + bh * (D * D);
    #pragma unroll
    for (int i = 0; i < 4; ++i)
        #pragma unroll
        for (int j = 0; j < 4; ++j)
            atomicAdd(&kvb[(dg * 4 + i) * 64 + eg * 4 + j], acc[i][j]);
}

// ---------------------------------------------------------------------------
// Kernel 4: KWT[b][c][h*64+d] = sum_e kv[bh][d][e] * Wp[c][h*64+e]   (bf16)
// grid = BH * (C/64) = 144 blocks, 256 threads, 4x4 tiles. Tiny (75 MFLOP).
// ---------------------------------------------------------------------------
__global__ __launch_bounds__(256) void kw_kernel(
    const float* __restrict__ kv, const float* __restrict__ Wp,
    unsigned short* __restrict__ KWT)
{
    __shared__ float kv_s[64 * 68];   // [e][d]
    __shared__ float w_s[64 * 68];    // [e][c]
    const int bh = blockIdx.x / (C / 64);
    const int ct = blockIdx.x % (C / 64);
    const int b = bh / H, h = bh % H;
    const int c0 = ct * 64;
    const int t = threadIdx.x, dg = t >> 4, cg = t & 15;

    for (int i = t; i < 4096; i += 256) {
        int row = i >> 6, e = i & 63;
        kv_s[e * 68 + row] = kv[bh * (D * D) + row * 64 + e];
        w_s[e * 68 + row]  = Wp[(size_t)(c0 + row) * C + h * 64 + e];
    }
    __syncthreads();

    float acc[4][4] = {};
    for (int e = 0; e < 64; ++e) {
        float4 a = *(float4*)&kv_s[e * 68 + dg * 4];
        float4 w = *(float4*)&w_s[e * 68 + cg * 4];
        const float a4[4] = {a.x, a.y, a.z, a.w};
        const float w4[4] = {w.x, w.y, w.z, w.w};
        #pragma unroll
        for (int i = 0; i < 4; ++i)
            #pragma unroll
            for (int j = 0; j < 4; ++j) acc[i][j] += a4[i] * w4[j];
    }
    #pragma unroll
    for (int i = 0; i < 4; ++i)
        #pragma unroll
        for (int j = 0; j < 4; ++j) {
            int d = dg * 4 + i, c = c0 + cg * 4 + j;
            KWT[((size_t)b * C + c) * (H * D) + h * 64 + d] = f2bf(acc[i][j]);
        }
}

// ---------------------------------------------------------------------------
// Kernel 5 (MFMA): out[m][c] = sum_k q[m][k] * KWT[c][k] + bp[c]
// Block: 128x128 tile, 4 waves of 64x64 (4x4 frags of 16x16x32 bf16).
// K-chunk = 64 = one head; q's per-head k-slices are contiguous bf16.
// ---------------------------------------------------------------------------
__global__ __launch_bounds__(256) void out_gemm(
    const unsigned short* __restrict__ q, const unsigned short* __restrict__ KWT,
    const float* __restrict__ bp, float* __restrict__ out)
{
    __shared__ __align__(16) unsigned short A_s[128 * 72];  // [m][k], pad 72
    __shared__ __align__(16) unsigned short B_s[128 * 72];  // [c][k], pad 72

    const int mt = blockIdx.x / (C / 128);
    const int ct = blockIdx.x % (C / 128);
    const int m0 = mt * 128, c0 = ct * 128;
    const int b  = m0 >> 13;            // N = 8192
    const int n0 = m0 & (N - 1);
    const int t  = threadIdx.x;
    const int lane = t & 63;
    const int w  = t >> 6;
    const int wm = w >> 1, wn = w & 1;  // 2x2 wave grid
    const int lq = lane & 15;           // frag row/col
    const int qd = lane >> 4;           // frag k-quad

    f32x4 acc[4][4] = {};

    for (int h = 0; h < H; ++h) {
        if (h) __syncthreads();
        // Stage A (q rows) and B (KWT rows): 1024 16B-chunks each.
        const unsigned short* qb = q + (size_t)(b * H + h) * N * D + (size_t)n0 * D;
        const unsigned short* kb = KWT + ((size_t)b * C + c0) * (H * D) + h * 64;
        #pragma unroll
        for (int it = 0; it < 4; ++it) {
            int id = it * 256 + t;
            int r = id >> 3, c8 = id & 7;
            *(uint4*)&A_s[r * 72 + c8 * 8] = *(const uint4*)(qb + r * 64 + c8 * 8);
            *(uint4*)&B_s[r * 72 + c8 * 8] = *(const uint4*)(kb + (size_t)r * (H * D) + c8 * 8);
        }
        __syncthreads();

        #pragma unroll
        for (int kk = 0; kk < 64; kk += 32) {
            short8 af[4], bf[4];
            #pragma unroll
            for (int i = 0; i < 4; ++i)
                af[i] = *(short8*)&A_s[(wm * 64 + i * 16 + lq) * 72 + kk + qd * 8];
            #pragma unroll
            for (int j = 0; j < 4; ++j)
                bf[j] = *(short8*)&B_s[(wn * 64 + j * 16 + lq) * 72 + kk + qd * 8];
            #pragma unroll
            for (int i = 0; i < 4; ++i)
                #pragma unroll
                for (int j = 0; j < 4; ++j)
                    acc[i][j] = __builtin_amdgcn_mfma_f32_16x16x32_bf16(
                        af[i], bf[j], acc[i][j], 0, 0, 0);
        }
    }

    float bpv[4];
    #pragma unroll
    for (int j = 0; j < 4; ++j) bpv[j] = bp[c0 + wn * 64 + j * 16 + lq];

    #pragma unroll
    for (int i = 0; i < 4; ++i) {
        #pragma unroll
        for (int r = 0; r < 4; ++r) {
            size_t row = (size_t)m0 + wm * 64 + i * 16 + qd * 4 + r;
            float* orow = out + row * C + c0 + wn * 64;
            #pragma unroll
            for (int j = 0; j < 4; ++j)
                orow[j * 16 + lq] = acc[i][j][r] + bpv[j];
        }
    }
}

// ---------------------------------------------------------------------------
extern "C" void kernel_launch(void* const* d_in, const int* in_sizes, int n_in,
                              void* d_out, int out_size, void* d_ws, size_t ws_size,
                              hipStream_t stream)
{
    const float* x  = (const float*)d_in[0];
    const float* Wq = (const float*)d_in[1];
    const float* bq = (const float*)d_in[2];
    const float* Wk = (const float*)d_in[3];
    const float* bk = (const float*)d_in[4];
    const float* Wv = (const float*)d_in[5];
    const float* bv = (const float*)d_in[6];
    const float* Wp = (const float*)d_in[7];
    const float* bp = (const float*)d_in[8];
    float* out = (float*)d_out;

    const size_t SZ = (size_t)B * H * N * D;
    float* ws   = (float*)d_ws;
    unsigned short* q = (unsigned short*)ws;    // [BH, N, D] bf16 (uses SZ/2 floats)
    float* kraw = ws + SZ;                      // [BH, N, D]
    float* vs   = ws + 2 * SZ;                  // [BH, N, D]
    float* kv   = ws + 3 * SZ;                  // [BH, D, D]
    float* pm   = kv + BH * D * D;
    float* ps   = pm + BH * 16 * 64;
    float* mfin = ps + BH * 16 * 64;
    float* zinv = mfin + BH * 64;
    unsigned short* KWT = (unsigned short*)(zinv + BH * 64);  // [B, C, H*D] bf16

    proj_kernel<<<BH * (N / 64), 256, 0, stream>>>(x, Wq, bq, Wk, bk, Wv, bv,
                                                   q, kraw, vs);
    kstat_partial<<<BH * 16, 256, 0, stream>>>(kraw, pm, ps);
    kstat_final<<<BH, 64, 0, stream>>>(pm, ps, mfin, zinv);
    hipMemsetAsync(kv, 0, (size_t)BH * D * D * sizeof(float), stream);
    kv_kernel<<<BH * 32, 256, 0, stream>>>(kraw, vs, mfin, zinv, kv);
    kw_kernel<<<BH * (C / 64), 256, 0, stream>>>(kv, Wp, KWT);
    out_gemm<<<(BN / 128) * (C / 128), 256, 0, stream>>>(q, KWT, bp, out);
}

// Round 5
// 268.861 us; speedup vs baseline: 2.6171x; 1.1804x over previous
//
#include <hip/hip_runtime.h>
#include <hip/hip_bf16.h>

// EfficientAttention: B=4, N=8192, C=384, H=6, D=64
// Round 5: fix wprep transpose bug (round 4 stored W un-transposed; the MFMA
// B-operand needs B[e][d] = W[d][e]). Everything else identical to round 4.

#define B 4
#define N 8192
#define C 384
#define H 6
#define D 64
#define BH (B * H)   // 24
#define BN (B * N)   // 32768
#define NBLK (N / 64)  // 128 row-blocks per head

typedef __attribute__((ext_vector_type(8))) short short8;
typedef __attribute__((ext_vector_type(4))) float f32x4;

__device__ inline unsigned short f2bf(float f) {
    unsigned int u = __float_as_uint(f);
    unsigned int r = (u + 0x7fff + ((u >> 16) & 1)) >> 16;   // RNE
    return (unsigned short)r;
}
__device__ inline float bf2f(unsigned short h) {
    return __uint_as_float(((unsigned int)h) << 16);
}

// ---------------------------------------------------------------------------
// Kernel 0: transpose + hi/lo-split the three weight sets.
// Whi/Wlo layout: [mat][h][e][d] bf16, value = W[d][e]  (B-operand rows = e).
// grid = 3*H blocks, 64 threads.
// ---------------------------------------------------------------------------
__global__ void wprep(const float* __restrict__ Wq, const float* __restrict__ Wk,
                      const float* __restrict__ Wv,
                      unsigned short* __restrict__ Whi, unsigned short* __restrict__ Wlo)
{
    __shared__ float tmp[64][65];
    const int m = blockIdx.x / H;
    const int h = blockIdx.x % H;
    const float* in = (m == 0 ? Wq : m == 1 ? Wk : Wv) + h * 64 * 64;
    const int t = threadIdx.x;
    for (int d = 0; d < 64; ++d) tmp[d][t] = in[d * 64 + t];   // tmp[d][e]
    __syncthreads();
    const size_t base = ((size_t)(m * H + h)) * 64 * 64;
    for (int e = 0; e < 64; ++e) {
        float v = tmp[t][e];                    // W[d=t][e] -> out[e][d=t]  (FIXED)
        unsigned short hb = f2bf(v);
        Whi[base + e * 64 + t] = hb;
        Wlo[base + e * 64 + t] = f2bf(v - bf2f(hb));
    }
}

// ---------------------------------------------------------------------------
// Kernel 1 (MFMA): per-head QKV projection + q softmax + v scale + fused
// k column-stat partials. grid = BH * NBLK (3072), 256 threads.
// ---------------------------------------------------------------------------
__global__ __launch_bounds__(256) void proj_kernel(
    const float* __restrict__ x,
    const unsigned short* __restrict__ Whi, const unsigned short* __restrict__ Wlo,
    const float* __restrict__ bq, const float* __restrict__ bk,
    const float* __restrict__ bv,
    unsigned short* __restrict__ qout, float* __restrict__ kraw,
    float* __restrict__ vout, float* __restrict__ pm, float* __restrict__ ps)
{
    __shared__ __align__(16) char smem[72704];
    float* A_s = (float*)smem;                                  // [64][68] fp32
    unsigned short* W_s = (unsigned short*)(smem + 17408);      // 6x [64][72] bf16

    const int blk = blockIdx.x;
    const int nb  = blk % NBLK;
    const int bh  = blk / NBLK;
    const int b   = bh / H;
    const int h   = bh % H;
    const int n0  = nb * 64;
    const int t   = threadIdx.x;
    const int lane = t & 63;
    const int w   = t >> 6;
    const int lq  = lane & 15;
    const int qd  = lane >> 4;

    // ---- stage x tile (row-major, conflict-free) ----
    for (int id = t; id < 1024; id += 256) {
        int r = id >> 4, j = id & 15;
        *(float4*)&A_s[r * 68 + 4 * j] =
            *(const float4*)(x + (size_t)(b * N + n0 + r) * C + h * D + 4 * j);
    }
    // ---- stage 6 weight parts (straight copy, pad 72) ----
    {
        const size_t hb64 = (size_t)h * 64 * 64;
        for (int id = t; id < 512; id += 256) {
            int e = id >> 3, j = id & 7;
            #pragma unroll
            for (int m = 0; m < 3; ++m) {
                const size_t src = ((size_t)m * H) * 64 * 64 + hb64 + e * 64 + 8 * j;
                *(uint4*)&W_s[(2 * m) * 4608 + e * 72 + 8 * j] = *(const uint4*)(Whi + src);
                *(uint4*)&W_s[(2 * m + 1) * 4608 + e * 72 + 8 * j] = *(const uint4*)(Wlo + src);
            }
        }
    }
    __syncthreads();

    // ---- MFMA: wave w computes rows w*16..w*16+15, all 64 cols, 3 matrices ----
    f32x4 acc[3][4] = {};
    #pragma unroll
    for (int ck = 0; ck < 2; ++ck) {
        const float* ap = A_s + (w * 16 + lq) * 68 + ck * 32 + qd * 8;
        float av[8];
        *(float4*)&av[0] = *(const float4*)ap;
        *(float4*)&av[4] = *(const float4*)(ap + 4);
        short8 ahi, alo;
        #pragma unroll
        for (int i = 0; i < 8; ++i) {
            unsigned short hb = f2bf(av[i]);
            ahi[i] = (short)hb;
            alo[i] = (short)f2bf(av[i] - bf2f(hb));
        }
        #pragma unroll
        for (int m = 0; m < 3; ++m) {
            #pragma unroll
            for (int j = 0; j < 4; ++j) {
                const unsigned short* bp =
                    W_s + (2 * m) * 4608 + (j * 16 + lq) * 72 + ck * 32 + qd * 8;
                short8 bhi = *(const short8*)bp;
                short8 blo = *(const short8*)(bp + 4608);
                acc[m][j] = __builtin_amdgcn_mfma_f32_16x16x32_bf16(alo, bhi, acc[m][j], 0, 0, 0);
                acc[m][j] = __builtin_amdgcn_mfma_f32_16x16x32_bf16(ahi, blo, acc[m][j], 0, 0, 0);
                acc[m][j] = __builtin_amdgcn_mfma_f32_16x16x32_bf16(ahi, bhi, acc[m][j], 0, 0, 0);
            }
        }
    }
    __syncthreads();   // all MFMA LDS reads done -> safe to reuse smem

    // ---- epilogue buffers (alias smem) ----
    float* kbuf = (float*)smem;                                  // [64][68]
    float* vbuf = (float*)(smem + 17408);                        // [64][68]
    unsigned short* qbuf = (unsigned short*)(smem + 35840);      // [64][72]
    float* sm_ = (float*)(smem + 45056);                         // [4][64]
    float* ss_ = sm_ + 256;

    float bqv[4], bkv[4], bvv[4];
    #pragma unroll
    for (int j = 0; j < 4; ++j) {
        int col = j * 16 + lq;
        bqv[j] = bq[h * D + col];
        bkv[j] = bk[h * D + col];
        bvv[j] = bv[h * D + col];
    }

    #pragma unroll
    for (int r = 0; r < 4; ++r) {
        const int row = w * 16 + qd * 4 + r;
        float qv[4];
        #pragma unroll
        for (int j = 0; j < 4; ++j) qv[j] = acc[0][j][r] + bqv[j];
        float mx = fmaxf(fmaxf(qv[0], qv[1]), fmaxf(qv[2], qv[3]));
        #pragma unroll
        for (int msk = 1; msk < 16; msk <<= 1) mx = fmaxf(mx, __shfl_xor(mx, msk));
        float e0 = __expf(qv[0] - mx), e1 = __expf(qv[1] - mx);
        float e2 = __expf(qv[2] - mx), e3 = __expf(qv[3] - mx);
        float s = e0 + e1 + e2 + e3;
        #pragma unroll
        for (int msk = 1; msk < 16; msk <<= 1) s += __shfl_xor(s, msk);
        float inv = 1.f / s;
        qbuf[row * 72 + 0 * 16 + lq] = f2bf(e0 * inv);
        qbuf[row * 72 + 1 * 16 + lq] = f2bf(e1 * inv);
        qbuf[row * 72 + 2 * 16 + lq] = f2bf(e2 * inv);
        qbuf[row * 72 + 3 * 16 + lq] = f2bf(e3 * inv);
        #pragma unroll
        for (int j = 0; j < 4; ++j) {
            kbuf[row * 68 + j * 16 + lq] = acc[1][j][r] + bkv[j];
            vbuf[row * 68 + j * 16 + lq] = (acc[2][j][r] + bvv[j]) * 0.125f;
        }
    }
    __syncthreads();

    // ---- coalesced global writes ----
    const size_t gbase = (size_t)bh * N + n0;
    for (int id = t; id < 1024; id += 256) {
        int r = id >> 4, j = id & 15;
        *(float4*)&kraw[(gbase + r) * D + 4 * j] = *(float4*)&kbuf[r * 68 + 4 * j];
        *(float4*)&vout[(gbase + r) * D + 4 * j] = *(float4*)&vbuf[r * 68 + 4 * j];
    }
    for (int id = t; id < 512; id += 256) {
        int r = id >> 3, j = id & 7;
        *(uint4*)&qout[(gbase + r) * D + 8 * j] = *(uint4*)&qbuf[r * 72 + 8 * j];
    }

    // ---- fused k column-stat partials (online max / sum-exp over 64 rows) ----
    {
        const int col = t & 63, qg = t >> 6;
        float m = -1e30f, s = 0.f;
        for (int r = qg * 16; r < qg * 16 + 16; ++r) {
            float kval = kbuf[r * 68 + col];
            float mn = fmaxf(m, kval);
            s = s * __expf(m - mn) + __expf(kval - mn);
            m = mn;
        }
        sm_[qg * 64 + col] = m;
        ss_[qg * 64 + col] = s;
    }
    __syncthreads();
    if (t < 64) {
        float M = sm_[t], S = ss_[t];
        #pragma unroll
        for (int i = 1; i < 4; ++i) {
            float m2 = sm_[i * 64 + t], s2 = ss_[i * 64 + t];
            float mn = fmaxf(M, m2);
            S = S * __expf(M - mn) + s2 * __expf(m2 - mn);
            M = mn;
        }
        pm[((size_t)bh * NBLK + nb) * 64 + t] = M;
        ps[((size_t)bh * NBLK + nb) * 64 + t] = S;
    }
}

// ---------------------------------------------------------------------------
// Kernel 2: combine NBLK partials per column.
// ---------------------------------------------------------------------------
__global__ void kstat_final(const float* __restrict__ pm, const float* __restrict__ ps,
                            float* __restrict__ mfin, float* __restrict__ zinv)
{
    const int bh = blockIdx.x;
    const int d = threadIdx.x;
    float M = -1e30f, S = 0.f;
    for (int c = 0; c < NBLK; ++c) {
        float m2 = pm[((size_t)bh * NBLK + c) * 64 + d];
        float s2 = ps[((size_t)bh * NBLK + c) * 64 + d];
        float mn = fmaxf(M, m2);
        S = S * __expf(M - mn) + s2 * __expf(m2 - mn);
        M = mn;
    }
    mfin[bh * 64 + d] = M;
    zinv[bh * 64 + d] = 1.f / S;
}

// ---------------------------------------------------------------------------
// Kernel 3: kv[bh][d][e] = sum_n softmax_n(k)[n,d] * v[n,e]  (atomic partials)
// ---------------------------------------------------------------------------
__global__ __launch_bounds__(256) void kv_kernel(
    const float* __restrict__ kraw, const float* __restrict__ v,
    const float* __restrict__ mfin, const float* __restrict__ zinv,
    float* __restrict__ kv)
{
    const int bh = blockIdx.x >> 5;
    const int ch = blockIdx.x & 31;
    const int t = threadIdx.x;
    const int lane = t & 63;
    const int eg = t & 15;
    const int dg = t >> 4;

    __shared__ float k_s[64 * 64];
    __shared__ float v_s[64 * 64];

    const float mcol = mfin[bh * 64 + lane];
    const float zcol = zinv[bh * 64 + lane];

    const float* kb = kraw + ((size_t)bh * N + ch * 256) * D;
    const float* vb = v    + ((size_t)bh * N + ch * 256) * D;

    float acc[4][4] = {};

    for (int sub = 0; sub < 4; ++sub) {
        __syncthreads();
        for (int i = t; i < 64 * 64; i += 256) {
            k_s[i] = __expf(kb[sub * 64 * 64 + i] - mcol) * zcol;
            v_s[i] = vb[sub * 64 * 64 + i];
        }
        __syncthreads();
        for (int r = 0; r < 64; ++r) {
            float4 kf = *(float4*)&k_s[r * 64 + dg * 4];
            float4 vf = *(float4*)&v_s[r * 64 + eg * 4];
            const float kk[4] = {kf.x, kf.y, kf.z, kf.w};
            const float vv[4] = {vf.x, vf.y, vf.z, vf.w};
            #pragma unroll
            for (int i = 0; i < 4; ++i)
                #pragma unroll
                for (int j = 0; j < 4; ++j) acc[i][j] += kk[i] * vv[j];
        }
    }

    float* kvb = kv + bh * (D * D);
    #pragma unroll
    for (int i = 0; i < 4; ++i)
        #pragma unroll
        for (int j = 0; j < 4; ++j)
            atomicAdd(&kvb[(dg * 4 + i) * 64 + eg * 4 + j], acc[i][j]);
}

// ---------------------------------------------------------------------------
// Kernel 4: KWT[b][c][h*64+d] = sum_e kv[bh][d][e] * Wp[c][h*64+e]   (bf16)
// ---------------------------------------------------------------------------
__global__ __launch_bounds__(256) void kw_kernel(
    const float* __restrict__ kv, const float* __restrict__ Wp,
    unsigned short* __restrict__ KWT)
{
    __shared__ float kv_s[64 * 68];   // [e][d]
    __shared__ float w_s[64 * 68];    // [e][c]
    const int bh = blockIdx.x / (C / 64);
    const int ct = blockIdx.x % (C / 64);
    const int b = bh / H, h = bh % H;
    const int c0 = ct * 64;
    const int t = threadIdx.x, dg = t >> 4, cg = t & 15;

    for (int i = t; i < 4096; i += 256) {
        int row = i >> 6, e = i & 63;
        kv_s[e * 68 + row] = kv[bh * (D * D) + row * 64 + e];
        w_s[e * 68 + row]  = Wp[(size_t)(c0 + row) * C + h * 64 + e];
    }
    __syncthreads();

    float acc[4][4] = {};
    for (int e = 0; e < 64; ++e) {
        float4 a = *(float4*)&kv_s[e * 68 + dg * 4];
        float4 w = *(float4*)&w_s[e * 68 + cg * 4];
        const float a4[4] = {a.x, a.y, a.z, a.w};
        const float w4[4] = {w.x, w.y, w.z, w.w};
        #pragma unroll
        for (int i = 0; i < 4; ++i)
            #pragma unroll
            for (int j = 0; j < 4; ++j) acc[i][j] += a4[i] * w4[j];
    }
    #pragma unroll
    for (int i = 0; i < 4; ++i)
        #pragma unroll
        for (int j = 0; j < 4; ++j) {
            int d = dg * 4 + i, c = c0 + cg * 4 + j;
            KWT[((size_t)b * C + c) * (H * D) + h * 64 + d] = f2bf(acc[i][j]);
        }
}

// ---------------------------------------------------------------------------
// Kernel 5 (MFMA): out[m][c] = sum_k q[m][k] * KWT[c][k] + bp[c]
// ---------------------------------------------------------------------------
__global__ __launch_bounds__(256) void out_gemm(
    const unsigned short* __restrict__ q, const unsigned short* __restrict__ KWT,
    const float* __restrict__ bp, float* __restrict__ out)
{
    __shared__ __align__(16) unsigned short A_s[128 * 72];
    __shared__ __align__(16) unsigned short B_s[128 * 72];

    const int mt = blockIdx.x / (C / 128);
    const int ct = blockIdx.x % (C / 128);
    const int m0 = mt * 128, c0 = ct * 128;
    const int b  = m0 >> 13;
    const int n0 = m0 & (N - 1);
    const int t  = threadIdx.x;
    const int lane = t & 63;
    const int w  = t >> 6;
    const int wm = w >> 1, wn = w & 1;
    const int lq = lane & 15;
    const int qd = lane >> 4;

    f32x4 acc[4][4] = {};

    for (int h = 0; h < H; ++h) {
        if (h) __syncthreads();
        const unsigned short* qb = q + (size_t)(b * H + h) * N * D + (size_t)n0 * D;
        const unsigned short* kb = KWT + ((size_t)b * C + c0) * (H * D) + h * 64;
        #pragma unroll
        for (int it = 0; it < 4; ++it) {
            int id = it * 256 + t;
            int r = id >> 3, c8 = id & 7;
            *(uint4*)&A_s[r * 72 + c8 * 8] = *(const uint4*)(qb + r * 64 + c8 * 8);
            *(uint4*)&B_s[r * 72 + c8 * 8] = *(const uint4*)(kb + (size_t)r * (H * D) + c8 * 8);
        }
        __syncthreads();

        #pragma unroll
        for (int kk = 0; kk < 64; kk += 32) {
            short8 af[4], bf[4];
            #pragma unroll
            for (int i = 0; i < 4; ++i)
                af[i] = *(short8*)&A_s[(wm * 64 + i * 16 + lq) * 72 + kk + qd * 8];
            #pragma unroll
            for (int j = 0; j < 4; ++j)
                bf[j] = *(short8*)&B_s[(wn * 64 + j * 16 + lq) * 72 + kk + qd * 8];
            #pragma unroll
            for (int i = 0; i < 4; ++i)
                #pragma unroll
                for (int j = 0; j < 4; ++j)
                    acc[i][j] = __builtin_amdgcn_mfma_f32_16x16x32_bf16(
                        af[i], bf[j], acc[i][j], 0, 0, 0);
        }
    }

    float bpv[4];
    #pragma unroll
    for (int j = 0; j < 4; ++j) bpv[j] = bp[c0 + wn * 64 + j * 16 + lq];

    #pragma unroll
    for (int i = 0; i < 4; ++i) {
        #pragma unroll
        for (int r = 0; r < 4; ++r) {
            size_t row = (size_t)m0 + wm * 64 + i * 16 + qd * 4 + r;
            float* orow = out + row * C + c0 + wn * 64;
            #pragma unroll
            for (int j = 0; j < 4; ++j)
                orow[j * 16 + lq] = acc[i][j][r] + bpv[j];
        }
    }
}

// ---------------------------------------------------------------------------
extern "C" void kernel_launch(void* const* d_in, const int* in_sizes, int n_in,
                              void* d_out, int out_size, void* d_ws, size_t ws_size,
                              hipStream_t stream)
{
    const float* x  = (const float*)d_in[0];
    const float* Wq = (const float*)d_in[1];
    const float* bq = (const float*)d_in[2];
    const float* Wk = (const float*)d_in[3];
    const float* bk = (const float*)d_in[4];
    const float* Wv = (const float*)d_in[5];
    const float* bv = (const float*)d_in[6];
    const float* Wp = (const float*)d_in[7];
    const float* bp = (const float*)d_in[8];
    float* out = (float*)d_out;

    const size_t SZ = (size_t)B * H * N * D;
    float* ws   = (float*)d_ws;
    unsigned short* q = (unsigned short*)ws;    // [BH, N, D] bf16 (SZ floats reserved)
    float* kraw = ws + SZ;                      // [BH, N, D] fp32
    float* vs   = ws + 2 * SZ;                  // [BH, N, D] fp32
    float* kv   = ws + 3 * SZ;                  // [BH, D, D]
    float* pm   = kv + BH * D * D;              // [BH, NBLK, 64]
    float* ps   = pm + (size_t)BH * NBLK * 64;
    float* mfin = ps + (size_t)BH * NBLK * 64;  // [BH, 64]
    float* zinv = mfin + BH * 64;
    unsigned short* KWT = (unsigned short*)(zinv + BH * 64);       // [B, C, H*D] bf16
    unsigned short* Whi = KWT + (size_t)B * C * (H * D);           // [3,H,64,64] bf16
    unsigned short* Wlo = Whi + (size_t)3 * H * 64 * 64;

    wprep<<<3 * H, 64, 0, stream>>>(Wq, Wk, Wv, Whi, Wlo);
    proj_kernel<<<BH * NBLK, 256, 0, stream>>>(x, Whi, Wlo, bq, bk, bv,
                                               q, kraw, vs, pm, ps);
    kstat_final<<<BH, 64, 0, stream>>>(pm, ps, mfin, zinv);
    hipMemsetAsync(kv, 0, (size_t)BH * D * D * sizeof(float), stream);
    kv_kernel<<<BH * 32, 256, 0, stream>>>(kraw, vs, mfin, zinv, kv);
    kw_kernel<<<BH * (C / 64), 256, 0, stream>>>(kv, Wp, KWT);
    out_gemm<<<(BN / 128) * (C / 128), 256, 0, stream>>>(q, KWT, bp, out);
}

// Round 6
// 184.074 us; speedup vs baseline: 3.8226x; 1.4606x over previous
//
#include <hip/hip_runtime.h>
#include <hip/hip_bf16.h>

// EfficientAttention: B=4, N=8192, C=384, H=6, D=64
// Round 6: kv fused into proj (in-register C-layout->A-layout identity for the
// 16x16 tile; no max-subtraction needed since |k|<~6). kraw/vs tensors and
// kv_kernel/kstat_final dispatches eliminated. 4 kernels + 1 memset.

#define B 4
#define N 8192
#define C 384
#define H 6
#define D 64
#define BH (B * H)   // 24
#define BN (B * N)   // 32768

typedef __attribute__((ext_vector_type(8))) short short8;
typedef __attribute__((ext_vector_type(4))) float f32x4;

__device__ inline unsigned short f2bf(float f) {
    unsigned int u = __float_as_uint(f);
    unsigned int r = (u + 0x7fff + ((u >> 16) & 1)) >> 16;   // RNE
    return (unsigned short)r;
}
__device__ inline float bf2f(unsigned short h) {
    return __uint_as_float(((unsigned int)h) << 16);
}

// ---------------------------------------------------------------------------
// Kernel 0: transpose + hi/lo-split the three weight sets.
// Whi/Wlo layout: [mat][h][e][d] bf16, value = W[d][e]  (B-operand rows = e).
// ---------------------------------------------------------------------------
__global__ void wprep(const float* __restrict__ Wq, const float* __restrict__ Wk,
                      const float* __restrict__ Wv,
                      unsigned short* __restrict__ Whi, unsigned short* __restrict__ Wlo)
{
    __shared__ float tmp[64][65];
    const int m = blockIdx.x / H;
    const int h = blockIdx.x % H;
    const float* in = (m == 0 ? Wq : m == 1 ? Wk : Wv) + h * 64 * 64;
    const int t = threadIdx.x;
    for (int d = 0; d < 64; ++d) tmp[d][t] = in[d * 64 + t];   // tmp[d][e]
    __syncthreads();
    const size_t base = ((size_t)(m * H + h)) * 64 * 64;
    for (int e = 0; e < 64; ++e) {
        float v = tmp[t][e];                    // W[d=t][e] -> out[e][d=t]
        unsigned short hb = f2bf(v);
        Whi[base + e * 64 + t] = hb;
        Wlo[base + e * 64 + t] = f2bf(v - bf2f(hb));
    }
}

// ---------------------------------------------------------------------------
// Kernel 1 (MFMA): per-head QKV projection + q softmax + fused kv-partial
// accumulation (k softmax numerator) + S column sums.
// grid = BH * (N/256) = 768 blocks, 256 threads, 256 rows per block.
// LDS: A_s 17408 + W_s 55296 + qbuf 9216 = 81920 B -> 2 blocks/CU.
// ---------------------------------------------------------------------------
__global__ __launch_bounds__(256, 2) void proj_kernel(
    const float* __restrict__ x,
    const unsigned short* __restrict__ Whi, const unsigned short* __restrict__ Wlo,
    const float* __restrict__ bq, const float* __restrict__ bk,
    const float* __restrict__ bv,
    unsigned short* __restrict__ qout,
    float* __restrict__ kvraw, float* __restrict__ Sg)
{
    __shared__ __align__(16) char smem[81920];
    float* A_s = (float*)smem;                                  // [64][68] fp32
    unsigned short* W_s = (unsigned short*)(smem + 17408);      // 6x [64][72] bf16
    unsigned short* qbuf = (unsigned short*)(smem + 72704);     // [64][72] bf16
    // end-of-kernel overlays (A_s + W_s region, used after last MFMA):
    float* kvred = (float*)smem;                                // [4][64*66] fp32
    float* sred  = (float*)(smem + 67584);                      // [4][64] fp32

    const int blk = blockIdx.x;
    const int nb  = blk & 31;            // N/256 = 32 chunks
    const int bh  = blk >> 5;
    const int b   = bh / H;
    const int h   = bh % H;
    const int n0  = nb * 256;
    const int t   = threadIdx.x;
    const int lane = t & 63;
    const int w   = t >> 6;
    const int lq  = lane & 15;
    const int qd  = lane >> 4;

    // ---- stage 6 weight parts once (straight copy, pad 72) ----
    {
        const size_t hb64 = (size_t)h * 64 * 64;
        for (int id = t; id < 512; id += 256) {
            int e = id >> 3, j = id & 7;
            #pragma unroll
            for (int m = 0; m < 3; ++m) {
                const size_t src = ((size_t)m * H) * 64 * 64 + hb64 + e * 64 + 8 * j;
                *(uint4*)&W_s[(2 * m) * 4608 + e * 72 + 8 * j] = *(const uint4*)(Whi + src);
                *(uint4*)&W_s[(2 * m + 1) * 4608 + e * 72 + 8 * j] = *(const uint4*)(Wlo + src);
            }
        }
    }

    float bqv[4], bkv[4], bvv[4];
    #pragma unroll
    for (int j = 0; j < 4; ++j) {
        int col = j * 16 + lq;
        bqv[j] = bq[h * D + col];
        bkv[j] = bk[h * D + col];
        bvv[j] = bv[h * D + col];
    }

    f32x4 kvacc[4][4] = {};      // partial kv over this wave's rows (d,e tiles)
    float sacc[4] = {};          // partial S per column j*16+lq

    for (int sub = 0; sub < 4; ++sub) {
        __syncthreads();   // A_s safe to rewrite; qbuf copies of prev sub done
        const int ns = n0 + sub * 64;
        for (int id = t; id < 1024; id += 256) {
            int r = id >> 4, j = id & 15;
            *(float4*)&A_s[r * 68 + 4 * j] =
                *(const float4*)(x + (size_t)(b * N + ns + r) * C + h * D + 4 * j);
        }
        __syncthreads();

        // ---- q/k/v MFMA (split-bf16, fp32-grade) ----
        f32x4 acc[3][4] = {};
        #pragma unroll
        for (int ck = 0; ck < 2; ++ck) {
            const float* ap = A_s + (w * 16 + lq) * 68 + ck * 32 + qd * 8;
            float av[8];
            *(float4*)&av[0] = *(const float4*)ap;
            *(float4*)&av[4] = *(const float4*)(ap + 4);
            short8 ahi, alo;
            #pragma unroll
            for (int i = 0; i < 8; ++i) {
                unsigned short hb = f2bf(av[i]);
                ahi[i] = (short)hb;
                alo[i] = (short)f2bf(av[i] - bf2f(hb));
            }
            #pragma unroll
            for (int m = 0; m < 3; ++m) {
                #pragma unroll
                for (int j = 0; j < 4; ++j) {
                    const unsigned short* bp =
                        W_s + (2 * m) * 4608 + (j * 16 + lq) * 72 + ck * 32 + qd * 8;
                    short8 bhi = *(const short8*)bp;
                    short8 blo = *(const short8*)(bp + 4608);
                    acc[m][j] = __builtin_amdgcn_mfma_f32_16x16x32_bf16(alo, bhi, acc[m][j], 0, 0, 0);
                    acc[m][j] = __builtin_amdgcn_mfma_f32_16x16x32_bf16(ahi, blo, acc[m][j], 0, 0, 0);
                    acc[m][j] = __builtin_amdgcn_mfma_f32_16x16x32_bf16(ahi, bhi, acc[m][j], 0, 0, 0);
                }
            }
        }

        // ---- q: bias + softmax over 64 cols -> qbuf (bf16) ----
        #pragma unroll
        for (int r = 0; r < 4; ++r) {
            const int row = w * 16 + qd * 4 + r;
            float qv[4];
            #pragma unroll
            for (int j = 0; j < 4; ++j) qv[j] = acc[0][j][r] + bqv[j];
            float mx = fmaxf(fmaxf(qv[0], qv[1]), fmaxf(qv[2], qv[3]));
            #pragma unroll
            for (int msk = 1; msk < 16; msk <<= 1) mx = fmaxf(mx, __shfl_xor(mx, msk));
            float e0 = __expf(qv[0] - mx), e1 = __expf(qv[1] - mx);
            float e2 = __expf(qv[2] - mx), e3 = __expf(qv[3] - mx);
            float s = e0 + e1 + e2 + e3;
            #pragma unroll
            for (int msk = 1; msk < 16; msk <<= 1) s += __shfl_xor(s, msk);
            float inv = 1.f / s;
            qbuf[row * 72 + 0 * 16 + lq] = f2bf(e0 * inv);
            qbuf[row * 72 + 1 * 16 + lq] = f2bf(e1 * inv);
            qbuf[row * 72 + 2 * 16 + lq] = f2bf(e2 * inv);
            qbuf[row * 72 + 3 * 16 + lq] = f2bf(e3 * inv);
        }

        // ---- k': exp(k) (no max needed, |k|<~6); v: bias+scale. In-register
        // C-layout == A/B-layout for the 16x16 tile (identity lane mapping).
        short8 kfrag[4], vfrag[4];
        #pragma unroll
        for (int j = 0; j < 4; ++j) {
            float e0 = __expf(acc[1][j][0] + bkv[j]);
            float e1 = __expf(acc[1][j][1] + bkv[j]);
            float e2 = __expf(acc[1][j][2] + bkv[j]);
            float e3 = __expf(acc[1][j][3] + bkv[j]);
            float cs = e0 + e1 + e2 + e3;       // this thread's 4 rows
            cs += __shfl_xor(cs, 16);
            cs += __shfl_xor(cs, 32);           // sum over all 16 rows of wave
            sacc[j] += cs;
            kfrag[j] = short8{(short)f2bf(e0), (short)f2bf(e1),
                              (short)f2bf(e2), (short)f2bf(e3), 0, 0, 0, 0};
            float v0 = (acc[2][j][0] + bvv[j]) * 0.125f;
            float v1 = (acc[2][j][1] + bvv[j]) * 0.125f;
            float v2 = (acc[2][j][2] + bvv[j]) * 0.125f;
            float v3 = (acc[2][j][3] + bvv[j]) * 0.125f;
            vfrag[j] = short8{(short)f2bf(v0), (short)f2bf(v1),
                              (short)f2bf(v2), (short)f2bf(v3), 0, 0, 0, 0};
        }
        #pragma unroll
        for (int i = 0; i < 4; ++i)
            #pragma unroll
            for (int j = 0; j < 4; ++j)
                kvacc[i][j] = __builtin_amdgcn_mfma_f32_16x16x32_bf16(
                    kfrag[i], vfrag[j], kvacc[i][j], 0, 0, 0);

        __syncthreads();   // qbuf complete
        for (int id = t; id < 512; id += 256) {
            int r = id >> 3, j = id & 7;
            *(uint4*)&qout[((size_t)bh * N + ns + r) * D + 8 * j] =
                *(uint4*)&qbuf[r * 72 + 8 * j];
        }
    }

    __syncthreads();   // all A_s/W_s reads and qbuf copies done -> overlay

    // ---- cross-wave reduce of kv partials + S, then one atomic each ----
    #pragma unroll
    for (int i = 0; i < 4; ++i)
        #pragma unroll
        for (int j = 0; j < 4; ++j)
            #pragma unroll
            for (int r = 0; r < 4; ++r)
                kvred[w * 4224 + (i * 16 + qd * 4 + r) * 66 + j * 16 + lq] =
                    kvacc[i][j][r];
    if (qd == 0) {
        #pragma unroll
        for (int j = 0; j < 4; ++j) sred[w * 64 + j * 16 + lq] = sacc[j];
    }
    __syncthreads();

    for (int idx = t; idx < 4096; idx += 256) {
        int d = idx >> 6, e = idx & 63;
        float s = kvred[d * 66 + e] + kvred[4224 + d * 66 + e]
                + kvred[2 * 4224 + d * 66 + e] + kvred[3 * 4224 + d * 66 + e];
        atomicAdd(&kvraw[bh * 4096 + idx], s);
    }
    if (t < 64) {
        float s = sred[t] + sred[64 + t] + sred[128 + t] + sred[192 + t];
        atomicAdd(&Sg[bh * 64 + t], s);
    }
}

// ---------------------------------------------------------------------------
// Kernel 2: KWT[b][c][h*64+d] = sum_e (kvraw[bh][d][e]/S[d]) * Wp[c][h*64+e]
// grid = BH * (C/64) = 144 blocks, 256 threads, 4x4 tiles.
// ---------------------------------------------------------------------------
__global__ __launch_bounds__(256) void kw_kernel(
    const float* __restrict__ kvraw, const float* __restrict__ Sg,
    const float* __restrict__ Wp, unsigned short* __restrict__ KWT)
{
    __shared__ float kv_s[64 * 68];   // [e][d]
    __shared__ float w_s[64 * 68];    // [e][c]
    __shared__ float rS_s[64];
    const int bh = blockIdx.x / (C / 64);
    const int ct = blockIdx.x % (C / 64);
    const int b = bh / H, h = bh % H;
    const int c0 = ct * 64;
    const int t = threadIdx.x, dg = t >> 4, cg = t & 15;

    if (t < 64) rS_s[t] = 1.f / Sg[bh * 64 + t];
    __syncthreads();

    for (int i = t; i < 4096; i += 256) {
        int row = i >> 6, e = i & 63;
        kv_s[e * 68 + row] = kvraw[bh * (D * D) + row * 64 + e] * rS_s[row];
        w_s[e * 68 + row]  = Wp[(size_t)(c0 + row) * C + h * 64 + e];
    }
    __syncthreads();

    float acc[4][4] = {};
    for (int e = 0; e < 64; ++e) {
        float4 a = *(float4*)&kv_s[e * 68 + dg * 4];
        float4 w = *(float4*)&w_s[e * 68 + cg * 4];
        const float a4[4] = {a.x, a.y, a.z, a.w};
        const float w4[4] = {w.x, w.y, w.z, w.w};
        #pragma unroll
        for (int i = 0; i < 4; ++i)
            #pragma unroll
            for (int j = 0; j < 4; ++j) acc[i][j] += a4[i] * w4[j];
    }
    #pragma unroll
    for (int i = 0; i < 4; ++i)
        #pragma unroll
        for (int j = 0; j < 4; ++j) {
            int d = dg * 4 + i, c = c0 + cg * 4 + j;
            KWT[((size_t)b * C + c) * (H * D) + h * 64 + d] = f2bf(acc[i][j]);
        }
}

// ---------------------------------------------------------------------------
// Kernel 3 (MFMA): out[m][c] = sum_k q[m][k] * KWT[c][k] + bp[c]
// ---------------------------------------------------------------------------
__global__ __launch_bounds__(256) void out_gemm(
    const unsigned short* __restrict__ q, const unsigned short* __restrict__ KWT,
    const float* __restrict__ bp, float* __restrict__ out)
{
    __shared__ __align__(16) unsigned short A_s[128 * 72];
    __shared__ __align__(16) unsigned short B_s[128 * 72];

    const int mt = blockIdx.x / (C / 128);
    const int ct = blockIdx.x % (C / 128);
    const int m0 = mt * 128, c0 = ct * 128;
    const int b  = m0 >> 13;
    const int n0 = m0 & (N - 1);
    const int t  = threadIdx.x;
    const int lane = t & 63;
    const int w  = t >> 6;
    const int wm = w >> 1, wn = w & 1;
    const int lq = lane & 15;
    const int qd = lane >> 4;

    f32x4 acc[4][4] = {};

    for (int h = 0; h < H; ++h) {
        if (h) __syncthreads();
        const unsigned short* qb = q + (size_t)(b * H + h) * N * D + (size_t)n0 * D;
        const unsigned short* kb = KWT + ((size_t)b * C + c0) * (H * D) + h * 64;
        #pragma unroll
        for (int it = 0; it < 4; ++it) {
            int id = it * 256 + t;
            int r = id >> 3, c8 = id & 7;
            *(uint4*)&A_s[r * 72 + c8 * 8] = *(const uint4*)(qb + r * 64 + c8 * 8);
            *(uint4*)&B_s[r * 72 + c8 * 8] = *(const uint4*)(kb + (size_t)r * (H * D) + c8 * 8);
        }
        __syncthreads();

        #pragma unroll
        for (int kk = 0; kk < 64; kk += 32) {
            short8 af[4], bf[4];
            #pragma unroll
            for (int i = 0; i < 4; ++i)
                af[i] = *(short8*)&A_s[(wm * 64 + i * 16 + lq) * 72 + kk + qd * 8];
            #pragma unroll
            for (int j = 0; j < 4; ++j)
                bf[j] = *(short8*)&B_s[(wn * 64 + j * 16 + lq) * 72 + kk + qd * 8];
            #pragma unroll
            for (int i = 0; i < 4; ++i)
                #pragma unroll
                for (int j = 0; j < 4; ++j)
                    acc[i][j] = __builtin_amdgcn_mfma_f32_16x16x32_bf16(
                        af[i], bf[j], acc[i][j], 0, 0, 0);
        }
    }

    float bpv[4];
    #pragma unroll
    for (int j = 0; j < 4; ++j) bpv[j] = bp[c0 + wn * 64 + j * 16 + lq];

    #pragma unroll
    for (int i = 0; i < 4; ++i) {
        #pragma unroll
        for (int r = 0; r < 4; ++r) {
            size_t row = (size_t)m0 + wm * 64 + i * 16 + qd * 4 + r;
            float* orow = out + row * C + c0 + wn * 64;
            #pragma unroll
            for (int j = 0; j < 4; ++j)
                orow[j * 16 + lq] = acc[i][j][r] + bpv[j];
        }
    }
}

// ---------------------------------------------------------------------------
extern "C" void kernel_launch(void* const* d_in, const int* in_sizes, int n_in,
                              void* d_out, int out_size, void* d_ws, size_t ws_size,
                              hipStream_t stream)
{
    const float* x  = (const float*)d_in[0];
    const float* Wq = (const float*)d_in[1];
    const float* bq = (const float*)d_in[2];
    const float* Wk = (const float*)d_in[3];
    const float* bk = (const float*)d_in[4];
    const float* Wv = (const float*)d_in[5];
    const float* bv = (const float*)d_in[6];
    const float* Wp = (const float*)d_in[7];
    const float* bp = (const float*)d_in[8];
    float* out = (float*)d_out;

    const size_t SZ = (size_t)B * H * N * D;
    float* ws   = (float*)d_ws;
    unsigned short* q = (unsigned short*)ws;          // [BH, N, D] bf16
    float* kvraw = ws + SZ;                           // [BH, 64, 64] fp32
    float* Sg    = kvraw + (size_t)BH * D * D;        // [BH, 64] fp32
    unsigned short* KWT = (unsigned short*)(Sg + BH * 64);     // [B, C, H*D] bf16
    unsigned short* Whi = KWT + (size_t)B * C * (H * D);       // [3,H,64,64] bf16
    unsigned short* Wlo = Whi + (size_t)3 * H * 64 * 64;

    wprep<<<3 * H, 64, 0, stream>>>(Wq, Wk, Wv, Whi, Wlo);
    hipMemsetAsync(kvraw, 0, ((size_t)BH * D * D + BH * 64) * sizeof(float), stream);
    proj_kernel<<<BH * (N / 256), 256, 0, stream>>>(x, Whi, Wlo, bq, bk, bv,
                                                    q, kvraw, Sg);
    kw_kernel<<<BH * (C / 64), 256, 0, stream>>>(kvraw, Sg, Wp, KWT);
    out_gemm<<<(BN / 128) * (C / 128), 256, 0, stream>>>(q, KWT, bp, out);
}